// Round 1
// baseline (2804.603 us; speedup 1.0000x reference)
//
#include <hip/hip_runtime.h>

// ---------------------------------------------------------------------------
// GCNConv (PyG semantics) + relu + log_softmax on MI355X
//   x: [N,128] f32, edge_index: [2,E] int (32 or 64 - detected), W: [128,16],
//   b: [16], out: [N,16] f32 log_softmax
// ---------------------------------------------------------------------------

// Detect whether edge_index is stored as int64 (odd 32-bit words all zero for
// non-negative values < 2^31) or int32. Deterministic, device-side.
__global__ void detect_i64_kernel(const unsigned int* __restrict__ ew, int* __restrict__ flag) {
    if (threadIdx.x == 0 && blockIdx.x == 0) {
        int is64 = 1;
        for (int i = 0; i < 256; ++i) {
            if (ew[2 * i + 1] != 0u) { is64 = 0; break; }
        }
        *flag = is64;
    }
}

// h = x @ W   (N x 128) @ (128 x 16) -> (N x 16)
__global__ __launch_bounds__(256) void linear_kernel(const float* __restrict__ x,
                                                     const float* __restrict__ W,
                                                     float* __restrict__ h, int N) {
    __shared__ float Ws[128 * 16];
    __shared__ float Xs[16 * 129];   // +1 pad: avoid 4-way bank conflict on row reads
    int tid = threadIdx.x;
    for (int i = tid; i < 2048; i += 256) Ws[i] = W[i];
    long long rbase = (long long)blockIdx.x * 16;
    for (int i = tid; i < 2048; i += 256) {
        int row = i >> 7, k = i & 127;
        long long grow = rbase + row;
        Xs[row * 129 + k] = (grow < N) ? x[grow * 128 + k] : 0.f;
    }
    __syncthreads();
    int rl = tid >> 4, c = tid & 15;
    float acc = 0.f;
#pragma unroll
    for (int k = 0; k < 128; ++k)
        acc = fmaf(Xs[rl * 129 + k], Ws[k * 16 + c], acc);
    long long row = rbase + rl;
    if (row < N) h[row * 16 + c] = acc;
}

// cnt[col] += 1 over all edges (self-loop added later as +1)
__global__ void deg_kernel(const unsigned int* __restrict__ ew, const int* __restrict__ flag,
                           unsigned int* __restrict__ cnt, int E) {
    int e = blockIdx.x * blockDim.x + threadIdx.x;
    if (e >= E) return;
    int i64 = *flag;
    int cl = i64 ? (int)ew[2 * (E + e)] : (int)ew[E + e];
    atomicAdd(&cnt[cl], 1u);
}

// dis[i] = rsqrt(deg), and initialize out with the self-loop term h[i]/deg[i]
__global__ void disk_kernel(const unsigned int* __restrict__ cnt, const float* __restrict__ h,
                            float* __restrict__ dis, float* __restrict__ out, int N) {
    int i = blockIdx.x * blockDim.x + threadIdx.x;
    if (i >= N) return;
    float deg = (float)cnt[i] + 1.0f;   // +1 self-loop; always > 0
    float ds = rsqrtf(deg);
    dis[i] = ds;
    float s = ds * ds;                  // self-loop norm = 1/deg
    const float4* hv = (const float4*)(h + ((long long)i << 4));
    float4* ov = (float4*)(out + ((long long)i << 4));
#pragma unroll
    for (int q = 0; q < 4; ++q) {
        float4 a = hv[q];
        a.x *= s; a.y *= s; a.z *= s; a.w *= s;
        ov[q] = a;
    }
}

// out[col] += dis[row]*dis[col] * h[row]  for each edge
__global__ void scatter_kernel(const unsigned int* __restrict__ ew, const int* __restrict__ flag,
                               const float* __restrict__ dis, const float* __restrict__ h,
                               float* __restrict__ out, int E) {
    int e = blockIdx.x * blockDim.x + threadIdx.x;
    if (e >= E) return;
    int i64 = *flag;
    int r, cl;
    if (i64) { r = (int)ew[2 * e]; cl = (int)ew[2 * (E + e)]; }
    else     { r = (int)ew[e];     cl = (int)ew[E + e]; }
    float nrm = dis[r] * dis[cl];
    const float4* hv = (const float4*)(h + ((long long)r << 4));
    float4 h0 = hv[0], h1 = hv[1], h2 = hv[2], h3 = hv[3];
    float* o = out + ((long long)cl << 4);
    atomicAdd(o + 0,  nrm * h0.x); atomicAdd(o + 1,  nrm * h0.y);
    atomicAdd(o + 2,  nrm * h0.z); atomicAdd(o + 3,  nrm * h0.w);
    atomicAdd(o + 4,  nrm * h1.x); atomicAdd(o + 5,  nrm * h1.y);
    atomicAdd(o + 6,  nrm * h1.z); atomicAdd(o + 7,  nrm * h1.w);
    atomicAdd(o + 8,  nrm * h2.x); atomicAdd(o + 9,  nrm * h2.y);
    atomicAdd(o + 10, nrm * h2.z); atomicAdd(o + 11, nrm * h2.w);
    atomicAdd(o + 12, nrm * h3.x); atomicAdd(o + 13, nrm * h3.y);
    atomicAdd(o + 14, nrm * h3.z); atomicAdd(o + 15, nrm * h3.w);
}

// out = log_softmax(relu(out + b)) per row of 16; 16 lanes per row
__global__ void finalize_kernel(float* __restrict__ out, const float* __restrict__ b, int N) {
    int t = blockIdx.x * blockDim.x + threadIdx.x;
    int r = t >> 4, c = t & 15;
    if (r >= N) return;
    float v = out[t] + b[c];
    v = fmaxf(v, 0.f);
    float m = v;
#pragma unroll
    for (int off = 1; off < 16; off <<= 1) m = fmaxf(m, __shfl_xor(m, off, 16));
    float ex = expf(v - m);
    float s = ex;
#pragma unroll
    for (int off = 1; off < 16; off <<= 1) s += __shfl_xor(s, off, 16);
    out[t] = (v - m) - logf(s);
}

extern "C" void kernel_launch(void* const* d_in, const int* in_sizes, int n_in,
                              void* d_out, int out_size, void* d_ws, size_t ws_size,
                              hipStream_t stream) {
    const float* x        = (const float*)d_in[0];
    const unsigned int* ew = (const unsigned int*)d_in[1];
    const float* W        = (const float*)d_in[2];
    const float* b        = (const float*)d_in[3];
    float* out = (float*)d_out;

    int N = in_sizes[0] / 128;   // 100000
    int E = in_sizes[1] / 2;     // 3200000

    char* wsb = (char*)d_ws;
    int* flag          = (int*)wsb;                          // 4 B (256 reserved)
    unsigned int* cnt  = (unsigned int*)(wsb + 256);         // N * 4
    float* dis         = (float*)(wsb + 256 + (size_t)N * 4);// N * 4
    float* h           = (float*)(wsb + 256 + (size_t)N * 8);// N * 16 * 4

    hipMemsetAsync(cnt, 0, (size_t)N * 4, stream);
    detect_i64_kernel<<<1, 64, 0, stream>>>(ew, flag);
    linear_kernel<<<(N + 15) / 16, 256, 0, stream>>>(x, W, h, N);
    deg_kernel<<<(E + 255) / 256, 256, 0, stream>>>(ew, flag, cnt, E);
    disk_kernel<<<(N + 255) / 256, 256, 0, stream>>>(cnt, h, dis, out, N);
    scatter_kernel<<<(E + 255) / 256, 256, 0, stream>>>(ew, flag, dis, h, out, E);
    finalize_kernel<<<(N * 16 + 255) / 256, 256, 0, stream>>>(out, b, N);
}

// Round 2
// 567.414 us; speedup vs baseline: 4.9428x; 4.9428x over previous
//
#include <hip/hip_runtime.h>

// ---------------------------------------------------------------------------
// GCNConv (PyG semantics) + relu + log_softmax on MI355X — CSR formulation.
//   x: [N,128] f32, edge_index: [2,E] int (32/64 detected), W: [128,16],
//   b: [16], out: [N,16] f32 log_softmax.
// R1 lesson: 51.2M f32 atomics (scatter) = 2631us, WRITE_SIZE 1.6GB.
// R2: build CSR by target (2x 3.2M u32 atomics), then atomic-free segmented
// gather-reduce fused with self-loop + bias + relu + log_softmax.
// ---------------------------------------------------------------------------

typedef unsigned int u32;

__global__ void detect_i64_kernel(const u32* __restrict__ ew, int* __restrict__ flag) {
    if (threadIdx.x == 0 && blockIdx.x == 0) {
        int is64 = 1;
        for (int i = 0; i < 256; ++i) {
            if (ew[2 * i + 1] != 0u) { is64 = 0; break; }
        }
        *flag = is64;
    }
}

// h = x @ W   (N x 128) @ (128 x 16) -> (N x 16)
__global__ __launch_bounds__(256) void linear_kernel(const float* __restrict__ x,
                                                     const float* __restrict__ W,
                                                     float* __restrict__ h, int N) {
    __shared__ float Ws[128 * 16];
    __shared__ float Xs[16 * 129];
    int tid = threadIdx.x;
    for (int i = tid; i < 2048; i += 256) Ws[i] = W[i];
    long long rbase = (long long)blockIdx.x * 16;
    for (int i = tid; i < 2048; i += 256) {
        int row = i >> 7, k = i & 127;
        long long grow = rbase + row;
        Xs[row * 129 + k] = (grow < N) ? x[grow * 128 + k] : 0.f;
    }
    __syncthreads();
    int rl = tid >> 4, c = tid & 15;
    float acc = 0.f;
#pragma unroll
    for (int k = 0; k < 128; ++k)
        acc = fmaf(Xs[rl * 129 + k], Ws[k * 16 + c], acc);
    long long row = rbase + rl;
    if (row < N) h[row * 16 + c] = acc;
}

// cnt[col] += 1 over all edges
__global__ void count_kernel(const u32* __restrict__ ew, const int* __restrict__ flag,
                             u32* __restrict__ cnt, int E) {
    int e = blockIdx.x * blockDim.x + threadIdx.x;
    if (e >= E) return;
    int i64 = *flag;
    u32 cl = i64 ? ew[2 * (E + e)] : ew[E + e];
    atomicAdd(&cnt[cl], 1u);
}

// dis[i] = rsqrt(deg_i), deg_i = cnt[i] + 1 (self-loop)
__global__ void disk_kernel(const u32* __restrict__ cnt, float* __restrict__ dis, int N) {
    int i = blockIdx.x * blockDim.x + threadIdx.x;
    if (i >= N) return;
    dis[i] = rsqrtf((float)cnt[i] + 1.0f);
}

// ---- exclusive scan over cnt[0..N) -> start[], 1024 elems per block ----
__global__ __launch_bounds__(256) void scan_block_kernel(const u32* __restrict__ cnt,
                                                         u32* __restrict__ start,
                                                         u32* __restrict__ bsum, int N) {
    __shared__ u32 sm[256];
    int t = threadIdx.x;
    int base = blockIdx.x * 1024 + t * 4;
    u32 v[4];
#pragma unroll
    for (int q = 0; q < 4; ++q) v[q] = (base + q < N) ? cnt[base + q] : 0u;
    u32 s = v[0] + v[1] + v[2] + v[3];
    sm[t] = s;
    __syncthreads();
    for (int d = 1; d < 256; d <<= 1) {
        u32 xv = (t >= d) ? sm[t - d] : 0u;
        __syncthreads();
        sm[t] += xv;
        __syncthreads();
    }
    u32 excl = sm[t] - s;
    if (t == 255) bsum[blockIdx.x] = sm[255];
    u32 run = excl;
#pragma unroll
    for (int q = 0; q < 4; ++q) {
        if (base + q < N) start[base + q] = run;
        run += v[q];
    }
}

__global__ void scan_total_kernel(u32* __restrict__ bsum, int nb) {
    if (threadIdx.x == 0 && blockIdx.x == 0) {
        u32 run = 0;
        for (int i = 0; i < nb; ++i) { u32 v = bsum[i]; bsum[i] = run; run += v; }
    }
}

__global__ void scan_add_kernel(u32* __restrict__ start, u32* __restrict__ cursor,
                                const u32* __restrict__ bsum, int N) {
    int i = blockIdx.x * blockDim.x + threadIdx.x;
    if (i >= N) return;
    u32 s = start[i] + bsum[i >> 10];
    start[i] = s;
    cursor[i] = s;
}

// erow[slot] = row, bucketed by col
__global__ void fill_kernel(const u32* __restrict__ ew, const int* __restrict__ flag,
                            u32* __restrict__ cursor, u32* __restrict__ erow, int E) {
    int e = blockIdx.x * blockDim.x + threadIdx.x;
    if (e >= E) return;
    int i64 = *flag;
    u32 r, cl;
    if (i64) { r = ew[2 * e]; cl = ew[2 * (E + e)]; }
    else     { r = ew[e];     cl = ew[E + e]; }
    u32 slot = atomicAdd(&cursor[cl], 1u);
    erow[slot] = r;
}

// One 64-lane wave per node: lane = j*16 + c (4 edge slots x 16 channels).
// acc_c = sum_edges norm * h[row*16+c]; + self-loop + bias + relu + log_softmax.
__global__ __launch_bounds__(256) void gather_kernel(const u32* __restrict__ erow,
                                                     const float* __restrict__ dis,
                                                     const float* __restrict__ h,
                                                     const u32* __restrict__ start,
                                                     const u32* __restrict__ cnt,
                                                     const float* __restrict__ b,
                                                     float* __restrict__ out, int N) {
    int node = blockIdx.x * 4 + (threadIdx.x >> 6);
    if (node >= N) return;
    int lane = threadIdx.x & 63;
    int c = lane & 15, j = lane >> 4;
    u32 s0 = start[node];
    u32 deg = cnt[node];
    float dc = dis[node];
    float acc = 0.f;
    for (u32 t = j; t < deg; t += 4) {
        u32 r = erow[s0 + t];
        float nrm = dis[r] * dc;
        acc = fmaf(nrm, h[(size_t)r * 16 + c], acc);
    }
    // reduce the 4 j-slots (all lanes end with full channel sum)
    acc += __shfl_xor(acc, 16, 64);
    acc += __shfl_xor(acc, 32, 64);
    // self-loop (norm = 1/deg) + bias
    float v = acc + h[(size_t)node * 16 + c] * (dc * dc) + b[c];
    v = fmaxf(v, 0.f);
    // log_softmax across the 16 channels
    float m = v;
#pragma unroll
    for (int off = 1; off < 16; off <<= 1) m = fmaxf(m, __shfl_xor(m, off, 16));
    float ex = expf(v - m);
    float ssum = ex;
#pragma unroll
    for (int off = 1; off < 16; off <<= 1) ssum += __shfl_xor(ssum, off, 16);
    if (j == 0) out[(size_t)node * 16 + c] = (v - m) - logf(ssum);
}

extern "C" void kernel_launch(void* const* d_in, const int* in_sizes, int n_in,
                              void* d_out, int out_size, void* d_ws, size_t ws_size,
                              hipStream_t stream) {
    const float* x  = (const float*)d_in[0];
    const u32*   ew = (const u32*)d_in[1];
    const float* W  = (const float*)d_in[2];
    const float* b  = (const float*)d_in[3];
    float* out = (float*)d_out;

    int N = in_sizes[0] / 128;   // 100000
    int E = in_sizes[1] / 2;     // 3200000

    char* wsb = (char*)d_ws;
    size_t off = 0;
    int* flag    = (int*)(wsb + off);  off += 256;
    u32* cnt     = (u32*)(wsb + off);  off += (size_t)N * 4;
    float* dis   = (float*)(wsb + off); off += (size_t)N * 4;
    u32* start   = (u32*)(wsb + off);  off += (size_t)N * 4;
    u32* cursor  = (u32*)(wsb + off);  off += (size_t)N * 4;
    u32* bsum    = (u32*)(wsb + off);  off += 4096;
    float* h     = (float*)(wsb + off); off += (size_t)N * 64;
    u32* erow    = (u32*)(wsb + off);  off += (size_t)E * 4;

    int nb = (N + 1023) / 1024;  // scan blocks

    hipMemsetAsync(cnt, 0, (size_t)N * 4, stream);
    detect_i64_kernel<<<1, 64, 0, stream>>>(ew, flag);
    linear_kernel<<<(N + 15) / 16, 256, 0, stream>>>(x, W, h, N);
    count_kernel<<<(E + 255) / 256, 256, 0, stream>>>(ew, flag, cnt, E);
    disk_kernel<<<(N + 255) / 256, 256, 0, stream>>>(cnt, dis, N);
    scan_block_kernel<<<nb, 256, 0, stream>>>(cnt, start, bsum, N);
    scan_total_kernel<<<1, 64, 0, stream>>>(bsum, nb);
    scan_add_kernel<<<(N + 255) / 256, 256, 0, stream>>>(start, cursor, bsum, N);
    fill_kernel<<<(E + 255) / 256, 256, 0, stream>>>(ew, flag, cursor, erow, E);
    gather_kernel<<<(N + 3) / 4, 256, 0, stream>>>(erow, dis, h, start, cnt, b, out, N);
}

// Round 3
// 469.080 us; speedup vs baseline: 5.9789x; 1.2096x over previous
//
#include <hip/hip_runtime.h>

// ---------------------------------------------------------------------------
// GCNConv (PyG) + relu + log_softmax, MI355X.
// R2 lesson: fill_kernel's 3.2M returning atomics + random 4B scatters cost
// 280us (WRITE_SIZE 194MB). R3: bucketed counting-sort (128 cols/bucket,
// packed u32 row|col'<<17 — requires N<2^17) + per-bucket LDS-tile accumulate
// with fused finalize. No global f32 atomics; ~300k reserve atomics only.
// ---------------------------------------------------------------------------

typedef unsigned int u32;

#define CPB 128        // cols per bucket
#define CPB_LOG 7
#define CHUNK 8192     // edges per binning block

__global__ void detect_i64_kernel(const u32* __restrict__ ew, int* __restrict__ flag) {
    if (threadIdx.x == 0 && blockIdx.x == 0) {
        int is64 = 1;
        for (int i = 0; i < 256; ++i) {
            if (ew[2 * i + 1] != 0u) { is64 = 0; break; }
        }
        *flag = is64;
    }
}

// h = x @ W   (N x 128) @ (128 x 16) -> (N x 16)
__global__ __launch_bounds__(256) void linear_kernel(const float* __restrict__ x,
                                                     const float* __restrict__ W,
                                                     float* __restrict__ h, int N) {
    __shared__ float Ws[128 * 16];
    __shared__ float Xs[16 * 129];
    int tid = threadIdx.x;
    for (int i = tid; i < 2048; i += 256) Ws[i] = W[i];
    long long rbase = (long long)blockIdx.x * 16;
    for (int i = tid; i < 2048; i += 256) {
        int row = i >> 7, k = i & 127;
        long long grow = rbase + row;
        Xs[row * 129 + k] = (grow < N) ? x[grow * 128 + k] : 0.f;
    }
    __syncthreads();
    int rl = tid >> 4, c = tid & 15;
    float acc = 0.f;
#pragma unroll
    for (int k = 0; k < 128; ++k)
        acc = fmaf(Xs[rl * 129 + k], Ws[k * 16 + c], acc);
    long long row = rbase + rl;
    if (row < N) h[row * 16 + c] = acc;
}

// Per-chunk LDS histogram of coarse buckets -> global bucket counts.
__global__ __launch_bounds__(256) void hist_kernel(const u32* __restrict__ ew,
                                                   const int* __restrict__ flag,
                                                   u32* __restrict__ bcnt, int E, int NB) {
    __shared__ u32 hh[1024];
    int t = threadIdx.x;
    for (int i = t; i < NB; i += 256) hh[i] = 0;
    __syncthreads();
    int i64 = *flag;
    int cb = blockIdx.x * CHUNK;
    int ce = min(cb + CHUNK, E);
    for (int e = cb + t; e < ce; e += 256) {
        u32 cl = i64 ? ew[2 * (E + e)] : ew[E + e];
        atomicAdd(&hh[cl >> CPB_LOG], 1u);
    }
    __syncthreads();
    for (int i = t; i < NB; i += 256)
        if (hh[i]) atomicAdd(&bcnt[i], hh[i]);
}

// Single-block exclusive scan of NB (<1024) bucket counts.
__global__ __launch_bounds__(1024) void scan_kernel(const u32* __restrict__ bcnt,
                                                    u32* __restrict__ bstart,
                                                    u32* __restrict__ gcur, int NB) {
    __shared__ u32 sm[1024];
    int t = threadIdx.x;
    u32 v = (t < NB) ? bcnt[t] : 0u;
    sm[t] = v;
    __syncthreads();
    for (int d = 1; d < 1024; d <<= 1) {
        u32 x = (t >= d) ? sm[t - d] : 0u;
        __syncthreads();
        sm[t] += x;
        __syncthreads();
    }
    u32 excl = sm[t] - v;
    if (t < NB) { bstart[t] = excl; gcur[t] = excl; }
    if (t == NB - 1) bstart[NB] = excl + v;
}

// Re-read edges; reserve per-(block,bucket) ranges; scatter packed u32.
__global__ __launch_bounds__(256) void scatter_bin_kernel(const u32* __restrict__ ew,
                                                          const int* __restrict__ flag,
                                                          u32* __restrict__ gcur,
                                                          u32* __restrict__ binned, int E, int NB) {
    __shared__ u32 hist[1024];
    __shared__ u32 base[1024];
    int t = threadIdx.x;
    for (int i = t; i < NB; i += 256) hist[i] = 0;
    __syncthreads();
    int i64 = *flag;
    int cb = blockIdx.x * CHUNK;
    int ce = min(cb + CHUNK, E);
    for (int e = cb + t; e < ce; e += 256) {
        u32 cl = i64 ? ew[2 * (E + e)] : ew[E + e];
        atomicAdd(&hist[cl >> CPB_LOG], 1u);
    }
    __syncthreads();
    for (int i = t; i < NB; i += 256) {
        u32 c = hist[i];
        base[i] = c ? atomicAdd(&gcur[i], c) : 0u;
        hist[i] = 0;   // reuse as local cursor
    }
    __syncthreads();
    for (int e = cb + t; e < ce; e += 256) {
        u32 r, cl;
        if (i64) { r = ew[2 * e]; cl = ew[2 * (E + e)]; }
        else     { r = ew[e];     cl = ew[E + e]; }
        u32 bk = cl >> CPB_LOG;
        u32 pos = base[bk] + atomicAdd(&hist[bk], 1u);
        binned[pos] = r | ((cl & (CPB - 1)) << 17);   // N < 2^17
    }
}

// Per-bucket degree from binned data (atomic-free global), write dis.
__global__ __launch_bounds__(256) void deg_kernel(const u32* __restrict__ binned,
                                                  const u32* __restrict__ bstart,
                                                  float* __restrict__ dis, int N) {
    __shared__ u32 cnt[CPB];
    int b = blockIdx.x, t = threadIdx.x;
    if (t < CPB) cnt[t] = 0;
    __syncthreads();
    u32 s = bstart[b], e = bstart[b + 1];
    for (u32 i = s + t; i < e; i += 256)
        atomicAdd(&cnt[binned[i] >> 17], 1u);
    __syncthreads();
    int col = (b << CPB_LOG) + t;
    if (t < CPB && col < N) dis[col] = rsqrtf((float)cnt[t] + 1.0f);
}

// One block per bucket: LDS tile accumulate + fused self-loop/bias/relu/log_softmax.
__global__ __launch_bounds__(256) void accum_kernel(const u32* __restrict__ binned,
                                                    const u32* __restrict__ bstart,
                                                    const float* __restrict__ dis,
                                                    const float* __restrict__ h,
                                                    const float* __restrict__ bias,
                                                    float* __restrict__ out, int N) {
    __shared__ float tile[CPB * 16];   // 8 KB
    __shared__ float dt[CPB];
    int b = blockIdx.x, t = threadIdx.x;
    int cbase = b << CPB_LOG;
    for (int i = t; i < CPB * 16; i += 256) tile[i] = 0.f;
    if (t < CPB) {
        int col = cbase + t;
        dt[t] = (col < N) ? dis[col] : 0.f;
    }
    __syncthreads();
    u32 s = bstart[b], e = bstart[b + 1];
    int c = t & 15, g = t >> 4;   // 16 groups of 16 lanes
#pragma unroll 2
    for (u32 i = s + g; i < e; i += 16) {
        u32 p = binned[i];
        u32 r = p & 0x1FFFFu;
        u32 cl = p >> 17;
        float nrm = dis[r] * dt[cl];
        float hv = h[(size_t)r * 16 + c];
        atomicAdd(&tile[(cl << 4) + c], nrm * hv);
    }
    __syncthreads();
    for (int cl = g; cl < CPB; cl += 16) {
        int col = cbase + cl;
        if (col >= N) continue;
        float v = tile[(cl << 4) + c] + h[(size_t)col * 16 + c] * dt[cl] * dt[cl] + bias[c];
        v = fmaxf(v, 0.f);
        float m = v;
#pragma unroll
        for (int off = 1; off < 16; off <<= 1) m = fmaxf(m, __shfl_xor(m, off, 16));
        float ex = expf(v - m);
        float ss = ex;
#pragma unroll
        for (int off = 1; off < 16; off <<= 1) ss += __shfl_xor(ss, off, 16);
        out[(size_t)col * 16 + c] = (v - m) - logf(ss);
    }
}

extern "C" void kernel_launch(void* const* d_in, const int* in_sizes, int n_in,
                              void* d_out, int out_size, void* d_ws, size_t ws_size,
                              hipStream_t stream) {
    const float* x  = (const float*)d_in[0];
    const u32*   ew = (const u32*)d_in[1];
    const float* W  = (const float*)d_in[2];
    const float* b  = (const float*)d_in[3];
    float* out = (float*)d_out;

    int N = in_sizes[0] / 128;   // 100000  (must be < 2^17 for packing)
    int E = in_sizes[1] / 2;     // 3200000
    int NB = (N + CPB - 1) >> CPB_LOG;   // 782

    char* wsb = (char*)d_ws;
    size_t off = 0;
    int* flag    = (int*)(wsb + off);   off += 256;
    u32* bcnt    = (u32*)(wsb + off);   off += 4096;
    u32* bstart  = (u32*)(wsb + off);   off += 4096 + 4;
    u32* gcur    = (u32*)(wsb + off);   off += 4096;
    float* dis   = (float*)(wsb + off); off += (size_t)N * 4;
    float* h     = (float*)(wsb + off); off += (size_t)N * 64;
    u32* binned  = (u32*)(wsb + off);   off += (size_t)E * 4;

    int nchunks = (E + CHUNK - 1) / CHUNK;

    hipMemsetAsync(bcnt, 0, 4096, stream);
    detect_i64_kernel<<<1, 64, 0, stream>>>(ew, flag);
    linear_kernel<<<(N + 15) / 16, 256, 0, stream>>>(x, W, h, N);
    hist_kernel<<<nchunks, 256, 0, stream>>>(ew, flag, bcnt, E, NB);
    scan_kernel<<<1, 1024, 0, stream>>>(bcnt, bstart, gcur, NB);
    scatter_bin_kernel<<<nchunks, 256, 0, stream>>>(ew, flag, gcur, binned, E, NB);
    deg_kernel<<<NB, 256, 0, stream>>>(binned, bstart, dis, N);
    accum_kernel<<<NB, 256, 0, stream>>>(binned, bstart, dis, h, b, out, N);
}